// Round 6
// baseline (268.400 us; speedup 1.0000x reference)
//
#include <hip/hip_runtime.h>
#include <hip/hip_bf16.h>
#include <math.h>

#define VOLF 100.0f
#define FD 32
#define OUT_DIM 10
#define MAXN 320
#define MAX_LAUNCH_ITERS 4
#define KSPLIT 7
#define BM 64      // neurons per block in k_act0
#define BKQ 28     // 112 k's / 4 per block-chunk
#define SRW 4      // k_scan rows per wave
#define SRB 16     // k_scan rows per block (4 waves)
#define OB 128     // k_out partial blocks

// ---------------- K1: per-neuron preprocess ----------------
__global__ __launch_bounds__(256) void k_pre(
    const float* __restrict__ positions, const float* __restrict__ radii_in,
    const float* __restrict__ features, float* __restrict__ posx4,
    float* __restrict__ radii, float* __restrict__ e_iw, float* __restrict__ e_ow,
    float* __restrict__ fn, float* __restrict__ scal, int N)
{
    int i = blockIdx.x * blockDim.x + threadIdx.x;
    float my_iw = 0.0f, my_ow = 0.0f, my_r = 0.0f;
    if (i < N) {
        float px = fminf(fmaxf(positions[3*i+0], 0.1f), VOLF - 0.1f);
        float py = fminf(fmaxf(positions[3*i+1], 0.1f), VOLF - 0.1f);
        float pz = fminf(fmaxf(positions[3*i+2], 0.1f), VOLF - 0.1f);
        float sq = px*px + py*py + pz*pz;
        posx4[4*i+0] = px; posx4[4*i+1] = py; posx4[4*i+2] = pz; posx4[4*i+3] = sq;
        float r = fminf(fmaxf(radii_in[i], 1.0f), 50.0f);
        radii[i] = r; my_r = r;
        float xc = fminf(fmaxf(px / VOLF, 0.0f), 1.0f);
        my_iw = expf(-3.0f * xc);
        my_ow = expf(3.0f * (xc - 1.0f));
        e_iw[i] = my_iw; e_ow[i] = my_ow;
        float s = 0.0f;
        #pragma unroll
        for (int k = 0; k < FD; k++) { float v = features[(size_t)i*FD + k]; s += v*v; }
        float nrm = fmaxf(sqrtf(s), 1e-6f);
        #pragma unroll
        for (int k = 0; k < FD; k++) fn[(size_t)i*FD + k] = features[(size_t)i*FD + k] / nrm;
    }
    __shared__ float red[256];
    red[threadIdx.x] = my_iw; __syncthreads();
    for (int s = 128; s > 0; s >>= 1) { if (threadIdx.x < s) red[threadIdx.x] += red[threadIdx.x + s]; __syncthreads(); }
    if (threadIdx.x == 0) atomicAdd(&scal[0], red[0]);
    __syncthreads();
    red[threadIdx.x] = my_ow; __syncthreads();
    for (int s = 128; s > 0; s >>= 1) { if (threadIdx.x < s) red[threadIdx.x] += red[threadIdx.x + s]; __syncthreads(); }
    if (threadIdx.x == 0) atomicAdd(&scal[1], red[0]);
    if (i < N) atomicMax((int*)&scal[2], __float_as_int(my_r));
}

// ---------------- K2: transpose x -> xT [IN][B] ----------------
__global__ __launch_bounds__(256) void k_xt(const float* __restrict__ x, float* __restrict__ xT,
                                            int B, int IN)
{
    int idx = blockIdx.x * blockDim.x + threadIdx.x;
    if (idx < B * IN) {
        int b = idx / IN, k = idx % IN;
        xT[(size_t)k * B + b] = x[idx];
    }
}

// ---------------- K3: LDS-tiled partial GEMM: partial[ks][N][64] ----------------
__global__ __launch_bounds__(256) void k_act0(
    const float* __restrict__ xT, const float* __restrict__ Wi,
    float* __restrict__ partial, int N, int IN)
{
    __shared__ float4 xs4[BKQ * 64];       // [kq][lane] = xT[k0+4kq..+3][lane]
    __shared__ float  wt[BM * 112];        // [row][k] row-major, 448B rows
    int t = threadIdx.x;
    int i0 = blockIdx.x * BM;
    int k0 = blockIdx.y * 112;
    // stage W tile: 64 rows x 112 floats, coalesced float4
    #pragma unroll
    for (int fi = t; fi < BM * 28; fi += 256) {
        int row = fi / 28, cq = fi % 28;
        ((float4*)wt)[row * 28 + cq] = *(const float4*)(Wi + (size_t)(i0 + row) * IN + k0 + cq * 4);
    }
    // stage xT chunk transposed into float4-per-lane
    {
        int l = t & 63, q = t >> 6;
        #pragma unroll
        for (int kq = q; kq < BKQ; kq += 4) {
            float4 v;
            v.x = xT[(size_t)(k0 + 4*kq + 0) * 64 + l];
            v.y = xT[(size_t)(k0 + 4*kq + 1) * 64 + l];
            v.z = xT[(size_t)(k0 + 4*kq + 2) * 64 + l];
            v.w = xT[(size_t)(k0 + 4*kq + 3) * 64 + l];
            xs4[kq * 64 + l] = v;
        }
    }
    __syncthreads();
    int wave = t >> 6, lane = t & 63;
    int nbase = wave * 16;
    float acc[16];
    #pragma unroll
    for (int n = 0; n < 16; n++) acc[n] = 0.0f;
    for (int kq = 0; kq < BKQ; kq++) {
        float4 xv = xs4[kq * 64 + lane];
        #pragma unroll
        for (int n = 0; n < 16; n++) {
            float4 w = ((const float4*)(wt + (nbase + n) * 112))[kq];
            acc[n] += w.x * xv.x + w.y * xv.y + w.z * xv.z + w.w * xv.w;
        }
    }
    size_t base = ((size_t)blockIdx.y * N + (i0 + nbase)) * 64 + lane;
    #pragma unroll
    for (int n = 0; n < 16; n++)
        partial[base + (size_t)n * 64] = acc[n];
}

// ---------------- K3b: reduce K-split partials, apply input gating ----------------
__global__ __launch_bounds__(256) void k_act0_red(
    const float* __restrict__ partial, const float* __restrict__ e_iw,
    const float* __restrict__ scal, float* __restrict__ actA, int N)
{
    int idx = blockIdx.x * 256 + threadIdx.x;   // over N*64
    int i = idx >> 6;
    size_t stride = (size_t)N * 64;
    float s = 0.0f;
    #pragma unroll
    for (int ks = 0; ks < KSPLIT; ks++) s += partial[ks * stride + idx];
    float inv = 1.0f / (scal[0] + 1e-6f);
    actA[idx] = s * (e_iw[i] * inv);
}

// ---------------- K4a: dense scan, wave-private compaction (no LDS/atomic/shfl) ----------------
__global__ __launch_bounds__(256) void k_scan(
    const float* __restrict__ posx4, const float* __restrict__ scal,
    int* __restrict__ nbr_idx, float* __restrict__ nbr_w /* dist out */,
    int* __restrict__ nbr_cnt, int N)
{
    int wave = threadIdx.x >> 6, lane = threadIdx.x & 63;
    int r0 = blockIdx.x * SRB + wave * SRW;
    float4 pi[SRW];
    #pragma unroll
    for (int t = 0; t < SRW; t++) pi[t] = ((const float4*)posx4)[r0 + t];
    float maxr = __int_as_float(((const int*)scal)[2]);
    unsigned long long lmask = (1ull << lane) - 1ull;
    int cnt[SRW] = {0, 0, 0, 0};
    for (int jb = 0; jb < N; jb += 64) {           // N multiple of 64
        int j = jb + lane;
        float4 pj = ((const float4*)posx4)[j];
        #pragma unroll
        for (int t = 0; t < SRW; t++) {
            float d2 = fmaxf(pi[t].w + pj.w - 2.0f*(pi[t].x*pj.x + pi[t].y*pj.y + pi[t].z*pj.z), 0.0f);
            float dist = sqrtf(d2);                // sqrt(0)=0 matches reference's where()
            bool hit = dist < maxr;
            unsigned long long m = __ballot(hit);
            if (m) {
                if (hit) {
                    int pos = cnt[t] + __popcll(m & lmask);
                    if (pos < MAXN) {
                        nbr_idx[(size_t)(r0 + t) * MAXN + pos] = j;
                        nbr_w [(size_t)(r0 + t) * MAXN + pos] = dist;
                    }
                }
                cnt[t] += (int)__popcll(m);        // wave-uniform update
            }
        }
    }
    if (lane == 0) {
        #pragma unroll
        for (int t = 0; t < SRW; t++)
            nbr_cnt[r0 + t] = min(cnt[t], MAXN);
    }
}

// ---------------- K4b: weight computation, 8 lanes per edge ----------------
__global__ __launch_bounds__(256) void k_weight(
    const float* __restrict__ fn, const float* __restrict__ radii,
    const int* __restrict__ nbr_idx, float* __restrict__ nbr_w /* in: dist, out: w */,
    const int* __restrict__ nbr_cnt, float* __restrict__ rowinv, int N)
{
    int i = blockIdx.x;
    int lane = threadIdx.x & 63;
    int wave = threadIdx.x >> 6;
    int sub = lane & 7;        // float4 slot within the edge's fn row
    int eg  = lane >> 3;       // edge-group within wave (8 edges/wave)
    float4 fni = ((const float4*)(fn + (size_t)i * FD))[sub];
    float inv_ri = 1.0f / (radii[i] + 1e-6f);
    int cnt = nbr_cnt[i];
    float s = 0.0f;
    for (int e0 = wave * 8; e0 < cnt; e0 += 32) {
        int e = e0 + eg;
        bool act = e < cnt;
        int ecl = act ? e : (cnt - 1);
        int j      = nbr_idx[(size_t)i * MAXN + ecl];
        float dist = nbr_w [(size_t)i * MAXN + ecl];
        float4 fj = ((const float4*)(fn + (size_t)j * FD))[sub];
        float fs = fni.x*fj.x + fni.y*fj.y + fni.z*fj.z + fni.w*fj.w;
        fs += __shfl_xor(fs, 1, 64);
        fs += __shfl_xor(fs, 2, 64);
        fs += __shfl_xor(fs, 4, 64);
        fs = fminf(fmaxf(fs, -1.0f), 1.0f);
        float w = expf(-fminf(dist * inv_ri, 20.0f)) * (0.3f + 0.7f * fs);
        if (act && sub == 0) {
            nbr_w[(size_t)i * MAXN + e] = w;
            s += w;
        }
    }
    __shared__ float red[256];
    red[threadIdx.x] = s; __syncthreads();
    for (int st = 128; st > 0; st >>= 1) { if (threadIdx.x < st) red[threadIdx.x] += red[threadIdx.x + st]; __syncthreads(); }
    if (threadIdx.x == 0) rowinv[i] = 1.0f / (red[0] + 1e-6f);
}

// ---------------- K5: one iteration (sparse matvec over 64 batches) ----------------
__global__ __launch_bounds__(256) void k_iter(
    const float* __restrict__ actIn, float* __restrict__ actOut,
    const int* __restrict__ nbr_idx, const float* __restrict__ nbr_w,
    const int* __restrict__ nbr_cnt, const float* __restrict__ rowinv,
    const float* __restrict__ thr,
    const int* __restrict__ nIterPtr, int iterIdx, int N)
{
    if (iterIdx >= min(*nIterPtr, MAX_LAUNCH_ITERS)) return;   // inactive launch: no-op
    int i = blockIdx.x;
    int wave = threadIdx.x >> 6, lane = threadIdx.x & 63;
    int cnt = nbr_cnt[i];
    float acc = 0.0f;
    for (int e = wave; e < cnt; e += 4) {
        int j   = nbr_idx[(size_t)i * MAXN + e];
        float w = nbr_w [(size_t)i * MAXN + e];
        acc += actIn[(size_t)j * 64 + lane] * w;
    }
    __shared__ float redA[4 * 64];
    redA[wave * 64 + lane] = acc;
    __syncthreads();
    if (wave == 0) {
        float tot = redA[lane] + redA[64 + lane] + redA[128 + lane] + redA[192 + lane];
        float v = actIn[(size_t)i * 64 + lane] + tot * rowinv[i] - thr[i];
        v = fminf(fmaxf(v, 0.0f), 100.0f);
        actOut[(size_t)i * 64 + lane] = v;
    }
}

// ---------------- K6a: output projection partials ----------------
__global__ __launch_bounds__(256) void k_out1(
    const float* __restrict__ actA, const float* __restrict__ actB,
    const int* __restrict__ nIterPtr, const float* __restrict__ e_ow,
    const float* __restrict__ scal, const float* __restrict__ outW,
    float* __restrict__ outPart, int N)
{
    int m = min(*nIterPtr, MAX_LAUNCH_ITERS);
    const float* actF = (m & 1) ? actB : actA;
    int wave = threadIdx.x >> 6, lane = threadIdx.x & 63;
    float inv = 1.0f / (scal[1] + 1e-6f);
    float acc[OUT_DIM];
    #pragma unroll
    for (int o = 0; o < OUT_DIM; o++) acc[o] = 0.0f;
    for (int i = blockIdx.x * 4 + wave; i < N; i += OB * 4) {
        float a = actF[(size_t)i * 64 + lane] * (e_ow[i] * inv);
        const float* wo = outW + (size_t)i * OUT_DIM;
        #pragma unroll
        for (int o = 0; o < OUT_DIM; o++) acc[o] += a * wo[o];
    }
    __shared__ float red[4][OUT_DIM][64];
    #pragma unroll
    for (int o = 0; o < OUT_DIM; o++) red[wave][o][lane] = acc[o];
    __syncthreads();
    if (wave == 0) {
        #pragma unroll
        for (int o = 0; o < OUT_DIM; o++) {
            float s = red[0][o][lane] + red[1][o][lane] + red[2][o][lane] + red[3][o][lane];
            outPart[((size_t)blockIdx.x * OUT_DIM + o) * 64 + lane] = s;
        }
    }
}

// ---------------- K6b: reduce partials -> out[b*10+o] ----------------
__global__ __launch_bounds__(256) void k_out2(
    const float* __restrict__ outPart, float* __restrict__ out)
{
    int t = blockIdx.x * 256 + threadIdx.x;     // over 640
    if (t >= 64 * OUT_DIM) return;
    int b = t / OUT_DIM, o = t % OUT_DIM;
    float s = 0.0f;
    for (int blk = 0; blk < OB; blk++)
        s += outPart[((size_t)blk * OUT_DIM + o) * 64 + b];
    out[t] = s;
}

extern "C" void kernel_launch(void* const* d_in, const int* in_sizes, int n_in,
                              void* d_out, int out_size, void* d_ws, size_t ws_size,
                              hipStream_t stream)
{
    const float* x        = (const float*)d_in[0];
    const float* positions= (const float*)d_in[1];
    const float* Win      = (const float*)d_in[2];
    const float* features = (const float*)d_in[3];
    const float* Wout     = (const float*)d_in[4];
    const float* radii_in = (const float*)d_in[5];
    const float* thr      = (const float*)d_in[6];
    const int*   nIter    = (const int*)  d_in[7];

    const int N  = in_sizes[5];            // 8000
    const int IN = in_sizes[2] / N;        // 784
    const int B  = in_sizes[0] / IN;       // 64 (kernels assume 64 = wave size)
    (void)B;

    float* ws = (float*)d_ws;
    size_t off = 0;
    auto alloc = [&](size_t nfloats) { size_t cur = off; off += (nfloats + 63) & ~(size_t)63; return cur; };
    float* xT      = ws + alloc((size_t)B * IN);
    float* posx4   = ws + alloc((size_t)N * 4);
    float* radii   = ws + alloc(N);
    float* e_iw    = ws + alloc(N);
    float* e_ow    = ws + alloc(N);
    float* rowinv  = ws + alloc(N);
    float* scal    = ws + alloc(4);
    float* outPart = ws + alloc((size_t)OB * OUT_DIM * 64);
    float* fn      = ws + alloc((size_t)N * FD);
    float* actA    = ws + alloc((size_t)N * 64);
    float* actB    = ws + alloc((size_t)N * 64);
    float* nbr_w   = ws + alloc((size_t)N * MAXN);
    int*   nbr_idx = (int*)(ws + alloc((size_t)N * MAXN));
    int*   nbr_cnt = (int*)(ws + alloc(N));
    // partial act0 [KSPLIT][N][64] aliased onto nbr_w+nbr_idx (consumed before k_scan writes them)
    float* partial = nbr_w;   // KSPLIT*N*64 = 3.584M floats <= 2*N*MAXN = 5.12M floats

    hipMemsetAsync(scal, 0, 4 * sizeof(float), stream);

    k_pre<<<(N + 255) / 256, 256, 0, stream>>>(positions, radii_in, features,
                                               posx4, radii, e_iw, e_ow, fn, scal, N);
    k_xt<<<(B * IN + 255) / 256, 256, 0, stream>>>(x, xT, B, IN);
    k_act0<<<dim3(N / BM, KSPLIT), 256, 0, stream>>>(xT, Win, partial, N, IN);
    k_act0_red<<<(N * 64) / 256, 256, 0, stream>>>(partial, e_iw, scal, actA, N);
    k_scan<<<N / SRB, 256, 0, stream>>>(posx4, scal, nbr_idx, nbr_w, nbr_cnt, N);
    k_weight<<<N, 256, 0, stream>>>(fn, radii, nbr_idx, nbr_w, nbr_cnt, rowinv, N);

    float* bufs[2] = {actA, actB};
    for (int it = 0; it < MAX_LAUNCH_ITERS; it++) {
        k_iter<<<N, 256, 0, stream>>>(bufs[it & 1], bufs[(it + 1) & 1],
                                      nbr_idx, nbr_w, nbr_cnt, rowinv, thr, nIter, it, N);
    }
    k_out1<<<OB, 256, 0, stream>>>(actA, actB, nIter, e_ow, scal, Wout, outPart, N);
    k_out2<<<3, 256, 0, stream>>>(outPart, (float*)d_out);
}

// Round 9
// 254.438 us; speedup vs baseline: 1.0549x; 1.0549x over previous
//
#include <hip/hip_runtime.h>
#include <hip/hip_bf16.h>
#include <math.h>

#define VOLF 100.0f
#define FD 32
#define OUT_DIM 10
#define MAXN 320
#define MAX_LAUNCH_ITERS 4
#define KSPLIT 7
#define BM 64      // neurons per block in k_act0
#define BKQ 28     // 112 k's / 4 per block-chunk
#define SRW 2      // k_scan rows per wave
#define SRB 8      // k_scan rows per block (4 waves)
#define OB 128     // k_out partial blocks

// ---------------- K1: per-neuron preprocess ----------------
__global__ __launch_bounds__(256) void k_pre(
    const float* __restrict__ positions, const float* __restrict__ radii_in,
    const float* __restrict__ features, float* __restrict__ posx4,
    float* __restrict__ radii, float* __restrict__ e_iw, float* __restrict__ e_ow,
    float* __restrict__ fn, float* __restrict__ scal, int N)
{
    int i = blockIdx.x * blockDim.x + threadIdx.x;
    float my_iw = 0.0f, my_ow = 0.0f, my_r = 0.0f;
    if (i < N) {
        float px = fminf(fmaxf(positions[3*i+0], 0.1f), VOLF - 0.1f);
        float py = fminf(fmaxf(positions[3*i+1], 0.1f), VOLF - 0.1f);
        float pz = fminf(fmaxf(positions[3*i+2], 0.1f), VOLF - 0.1f);
        float sq = px*px + py*py + pz*pz;
        posx4[4*i+0] = px; posx4[4*i+1] = py; posx4[4*i+2] = pz; posx4[4*i+3] = sq;
        float r = fminf(fmaxf(radii_in[i], 1.0f), 50.0f);
        radii[i] = r; my_r = r;
        float xc = fminf(fmaxf(px / VOLF, 0.0f), 1.0f);
        my_iw = expf(-3.0f * xc);
        my_ow = expf(3.0f * (xc - 1.0f));
        e_iw[i] = my_iw; e_ow[i] = my_ow;
        float s = 0.0f;
        #pragma unroll
        for (int k = 0; k < FD; k++) { float v = features[(size_t)i*FD + k]; s += v*v; }
        float nrm = fmaxf(sqrtf(s), 1e-6f);
        #pragma unroll
        for (int k = 0; k < FD; k++) fn[(size_t)i*FD + k] = features[(size_t)i*FD + k] / nrm;
    }
    __shared__ float red[256];
    red[threadIdx.x] = my_iw; __syncthreads();
    for (int s = 128; s > 0; s >>= 1) { if (threadIdx.x < s) red[threadIdx.x] += red[threadIdx.x + s]; __syncthreads(); }
    if (threadIdx.x == 0) atomicAdd(&scal[0], red[0]);
    __syncthreads();
    red[threadIdx.x] = my_ow; __syncthreads();
    for (int s = 128; s > 0; s >>= 1) { if (threadIdx.x < s) red[threadIdx.x] += red[threadIdx.x + s]; __syncthreads(); }
    if (threadIdx.x == 0) atomicAdd(&scal[1], red[0]);
    if (i < N) atomicMax((int*)&scal[2], __float_as_int(my_r));
}

// ---------------- K2: transpose x -> xT [IN][B] ----------------
__global__ __launch_bounds__(256) void k_xt(const float* __restrict__ x, float* __restrict__ xT,
                                            int B, int IN)
{
    int idx = blockIdx.x * blockDim.x + threadIdx.x;
    if (idx < B * IN) {
        int b = idx / IN, k = idx % IN;
        xT[(size_t)k * B + b] = x[idx];
    }
}

// ---------------- K3: LDS-tiled partial GEMM: partial[ks][N][64] ----------------
__global__ __launch_bounds__(256) void k_act0(
    const float* __restrict__ xT, const float* __restrict__ Wi,
    float* __restrict__ partial, int N, int IN)
{
    __shared__ float4 xs4[BKQ * 64];       // [kq][lane] = xT[k0+4kq..+3][lane]
    __shared__ float  wt[BM * 112];        // [row][k] row-major, 448B rows
    int t = threadIdx.x;
    int i0 = blockIdx.x * BM;
    int k0 = blockIdx.y * 112;
    // stage W tile: 64 rows x 112 floats, coalesced float4
    #pragma unroll
    for (int fi = t; fi < BM * 28; fi += 256) {
        int row = fi / 28, cq = fi % 28;
        ((float4*)wt)[row * 28 + cq] = *(const float4*)(Wi + (size_t)(i0 + row) * IN + k0 + cq * 4);
    }
    // stage xT chunk transposed into float4-per-lane
    {
        int l = t & 63, q = t >> 6;
        #pragma unroll
        for (int kq = q; kq < BKQ; kq += 4) {
            float4 v;
            v.x = xT[(size_t)(k0 + 4*kq + 0) * 64 + l];
            v.y = xT[(size_t)(k0 + 4*kq + 1) * 64 + l];
            v.z = xT[(size_t)(k0 + 4*kq + 2) * 64 + l];
            v.w = xT[(size_t)(k0 + 4*kq + 3) * 64 + l];
            xs4[kq * 64 + l] = v;
        }
    }
    __syncthreads();
    int wave = t >> 6, lane = t & 63;
    int nbase = wave * 16;
    float acc[16];
    #pragma unroll
    for (int n = 0; n < 16; n++) acc[n] = 0.0f;
    for (int kq = 0; kq < BKQ; kq++) {
        float4 xv = xs4[kq * 64 + lane];
        #pragma unroll
        for (int n = 0; n < 16; n++) {
            float4 w = ((const float4*)(wt + (nbase + n) * 112))[kq];
            acc[n] += w.x * xv.x + w.y * xv.y + w.z * xv.z + w.w * xv.w;
        }
    }
    size_t base = ((size_t)blockIdx.y * N + (i0 + nbase)) * 64 + lane;
    #pragma unroll
    for (int n = 0; n < 16; n++)
        partial[base + (size_t)n * 64] = acc[n];
}

// ---------------- K3b: reduce K-split partials, apply input gating ----------------
__global__ __launch_bounds__(256) void k_act0_red(
    const float* __restrict__ partial, const float* __restrict__ e_iw,
    const float* __restrict__ scal, float* __restrict__ actA, int N)
{
    int idx = blockIdx.x * 256 + threadIdx.x;   // over N*64
    int i = idx >> 6;
    size_t stride = (size_t)N * 64;
    float s = 0.0f;
    #pragma unroll
    for (int ks = 0; ks < KSPLIT; ks++) s += partial[ks * stride + idx];
    float inv = 1.0f / (scal[0] + 1e-6f);
    actA[idx] = s * (e_iw[i] * inv);
}

// ---------------- K4a helper: one (row, j-batch) body ----------------
// EXACT reference predicate: dist = sqrtf(max(d2,0)); hit = dist < maxr.
__device__ __forceinline__ void scan_body(
    const float4& p, const float4& q, int j, float maxr,
    unsigned long long lmask, int2* __restrict__ ep, size_t base, int& cnt)
{
    float d2 = fmaxf(p.w + q.w - 2.0f*(p.x*q.x + p.y*q.y + p.z*q.z), 0.0f);
    float dist = sqrtf(d2);                 // sqrt(0)=0 matches reference's where()
    bool hit = dist < maxr;
    unsigned long long m = __ballot(hit);
    if (m) {
        if (hit) {
            int pos = cnt + (int)__popcll(m & lmask);
            if (pos < MAXN) ep[base + pos] = make_int2(j, __float_as_int(dist));
        }
        cnt += (int)__popcll(m);   // wave-uniform
    }
}

// ---------------- K4a: dense scan, packed (j,dist) stores, wave-private counts ----------------
// NOTE: N = 8000 is a multiple of 64 but NOT of 128 — main loop is 128-wide,
// tail loop covers the remaining 64-batch (round-7/8 OOB bug fix).
__global__ __launch_bounds__(256) void k_scan(
    const float* __restrict__ posx4, const float* __restrict__ scal,
    int2* __restrict__ ep, int* __restrict__ nbr_cnt, int N)
{
    int wave = threadIdx.x >> 6, lane = threadIdx.x & 63;
    int r0 = blockIdx.x * SRB + wave * SRW;
    float4 p0 = ((const float4*)posx4)[r0];
    float4 p1 = ((const float4*)posx4)[r0 + 1];
    float maxr = __int_as_float(((const int*)scal)[2]);
    unsigned long long lmask = (1ull << lane) - 1ull;
    int c0 = 0, c1 = 0;
    size_t base0 = (size_t)r0 * MAXN, base1 = base0 + MAXN;
    int jb = 0;
    for (; jb + 128 <= N; jb += 128) {
        int j0 = jb + lane, j1 = jb + 64 + lane;
        float4 q0 = ((const float4*)posx4)[j0];
        float4 q1 = ((const float4*)posx4)[j1];
        scan_body(p0, q0, j0, maxr, lmask, ep, base0, c0);
        scan_body(p1, q0, j0, maxr, lmask, ep, base1, c1);
        scan_body(p0, q1, j1, maxr, lmask, ep, base0, c0);
        scan_body(p1, q1, j1, maxr, lmask, ep, base1, c1);
    }
    for (; jb < N; jb += 64) {             // tail (N multiple of 64)
        int j0 = jb + lane;
        float4 q0 = ((const float4*)posx4)[j0];
        scan_body(p0, q0, j0, maxr, lmask, ep, base0, c0);
        scan_body(p1, q0, j0, maxr, lmask, ep, base1, c1);
    }
    if (lane == 0) {
        nbr_cnt[r0]     = min(c0, MAXN);
        nbr_cnt[r0 + 1] = min(c1, MAXN);
    }
}

// ---------------- K4b: weight computation, 8 lanes per edge ----------------
__global__ __launch_bounds__(256) void k_weight(
    const float* __restrict__ fn, const float* __restrict__ radii,
    int2* __restrict__ ep /* in: (j,dist), out: (j,w) */,
    const int* __restrict__ nbr_cnt, float* __restrict__ rowinv, int N)
{
    int i = blockIdx.x;
    int lane = threadIdx.x & 63;
    int wave = threadIdx.x >> 6;
    int sub = lane & 7;        // float4 slot within the edge's fn row
    int eg  = lane >> 3;       // edge-group within wave (8 edges/wave)
    float4 fni = ((const float4*)(fn + (size_t)i * FD))[sub];
    float inv_ri = 1.0f / (radii[i] + 1e-6f);
    int cnt = nbr_cnt[i];
    float s = 0.0f;
    for (int e0 = wave * 8; e0 < cnt; e0 += 32) {
        int e = e0 + eg;
        bool act = e < cnt;
        int ecl = act ? e : (cnt - 1);
        int2 edge = ep[(size_t)i * MAXN + ecl];
        int j      = edge.x;
        float dist = __int_as_float(edge.y);
        float4 fj = ((const float4*)(fn + (size_t)j * FD))[sub];
        float fs = fni.x*fj.x + fni.y*fj.y + fni.z*fj.z + fni.w*fj.w;
        fs += __shfl_xor(fs, 1, 64);
        fs += __shfl_xor(fs, 2, 64);
        fs += __shfl_xor(fs, 4, 64);
        fs = fminf(fmaxf(fs, -1.0f), 1.0f);
        float w = expf(-fminf(dist * inv_ri, 20.0f)) * (0.3f + 0.7f * fs);
        if (act && sub == 0) {
            ((float*)&ep[(size_t)i * MAXN + e])[1] = w;
            s += w;
        }
    }
    __shared__ float red[256];
    red[threadIdx.x] = s; __syncthreads();
    for (int st = 128; st > 0; st >>= 1) { if (threadIdx.x < st) red[threadIdx.x] += red[threadIdx.x + st]; __syncthreads(); }
    if (threadIdx.x == 0) rowinv[i] = 1.0f / (red[0] + 1e-6f);
}

// ---------------- K5: one iteration (sparse matvec over 64 batches) ----------------
__global__ __launch_bounds__(256) void k_iter(
    const float* __restrict__ actIn, float* __restrict__ actOut,
    const int2* __restrict__ ep, const int* __restrict__ nbr_cnt,
    const float* __restrict__ rowinv, const float* __restrict__ thr,
    const int* __restrict__ nIterPtr, int iterIdx, int N)
{
    if (iterIdx >= min(*nIterPtr, MAX_LAUNCH_ITERS)) return;   // inactive launch: no-op
    int i = blockIdx.x;
    int wave = threadIdx.x >> 6, lane = threadIdx.x & 63;
    int cnt = nbr_cnt[i];
    float acc = 0.0f;
    for (int e = wave; e < cnt; e += 4) {
        int2 edge = ep[(size_t)i * MAXN + e];
        acc += actIn[(size_t)edge.x * 64 + lane] * __int_as_float(edge.y);
    }
    __shared__ float redA[4 * 64];
    redA[wave * 64 + lane] = acc;
    __syncthreads();
    if (wave == 0) {
        float tot = redA[lane] + redA[64 + lane] + redA[128 + lane] + redA[192 + lane];
        float v = actIn[(size_t)i * 64 + lane] + tot * rowinv[i] - thr[i];
        v = fminf(fmaxf(v, 0.0f), 100.0f);
        actOut[(size_t)i * 64 + lane] = v;
    }
}

// ---------------- K6a: output projection partials ----------------
__global__ __launch_bounds__(256) void k_out1(
    const float* __restrict__ actA, const float* __restrict__ actB,
    const int* __restrict__ nIterPtr, const float* __restrict__ e_ow,
    const float* __restrict__ scal, const float* __restrict__ outW,
    float* __restrict__ outPart, int N)
{
    int m = min(*nIterPtr, MAX_LAUNCH_ITERS);
    const float* actF = (m & 1) ? actB : actA;
    int wave = threadIdx.x >> 6, lane = threadIdx.x & 63;
    float inv = 1.0f / (scal[1] + 1e-6f);
    float acc[OUT_DIM];
    #pragma unroll
    for (int o = 0; o < OUT_DIM; o++) acc[o] = 0.0f;
    for (int i = blockIdx.x * 4 + wave; i < N; i += OB * 4) {
        float a = actF[(size_t)i * 64 + lane] * (e_ow[i] * inv);
        const float* wo = outW + (size_t)i * OUT_DIM;
        #pragma unroll
        for (int o = 0; o < OUT_DIM; o++) acc[o] += a * wo[o];
    }
    __shared__ float red[4][OUT_DIM][64];
    #pragma unroll
    for (int o = 0; o < OUT_DIM; o++) red[wave][o][lane] = acc[o];
    __syncthreads();
    if (wave == 0) {
        #pragma unroll
        for (int o = 0; o < OUT_DIM; o++) {
            float s = red[0][o][lane] + red[1][o][lane] + red[2][o][lane] + red[3][o][lane];
            outPart[((size_t)blockIdx.x * OUT_DIM + o) * 64 + lane] = s;
        }
    }
}

// ---------------- K6b: reduce partials -> out[b*10+o] ----------------
__global__ __launch_bounds__(256) void k_out2(
    const float* __restrict__ outPart, float* __restrict__ out)
{
    int t = blockIdx.x * 256 + threadIdx.x;     // over 640
    if (t >= 64 * OUT_DIM) return;
    int b = t / OUT_DIM, o = t % OUT_DIM;
    float s = 0.0f;
    for (int blk = 0; blk < OB; blk++)
        s += outPart[((size_t)blk * OUT_DIM + o) * 64 + b];
    out[t] = s;
}

extern "C" void kernel_launch(void* const* d_in, const int* in_sizes, int n_in,
                              void* d_out, int out_size, void* d_ws, size_t ws_size,
                              hipStream_t stream)
{
    const float* x        = (const float*)d_in[0];
    const float* positions= (const float*)d_in[1];
    const float* Win      = (const float*)d_in[2];
    const float* features = (const float*)d_in[3];
    const float* Wout     = (const float*)d_in[4];
    const float* radii_in = (const float*)d_in[5];
    const float* thr      = (const float*)d_in[6];
    const int*   nIter    = (const int*)  d_in[7];

    const int N  = in_sizes[5];            // 8000
    const int IN = in_sizes[2] / N;        // 784
    const int B  = in_sizes[0] / IN;       // 64 (kernels assume 64 = wave size)
    (void)B;

    float* ws = (float*)d_ws;
    size_t off = 0;
    auto alloc = [&](size_t nfloats) { size_t cur = off; off += (nfloats + 63) & ~(size_t)63; return cur; };
    float* xT      = ws + alloc((size_t)B * IN);
    float* posx4   = ws + alloc((size_t)N * 4);
    float* radii   = ws + alloc(N);
    float* e_iw    = ws + alloc(N);
    float* e_ow    = ws + alloc(N);
    float* rowinv  = ws + alloc(N);
    float* scal    = ws + alloc(4);
    float* outPart = ws + alloc((size_t)OB * OUT_DIM * 64);
    float* fn      = ws + alloc((size_t)N * FD);
    float* actA    = ws + alloc((size_t)N * 64);
    float* actB    = ws + alloc((size_t)N * 64);
    int2*  ep      = (int2*)(ws + alloc((size_t)N * MAXN * 2));   // packed (j, dist/w)
    int*   nbr_cnt = (int*)(ws + alloc(N));
    // partial act0 [KSPLIT][N][64] aliased onto ep (consumed before k_scan writes it)
    float* partial = (float*)ep;   // KSPLIT*N*64 = 3.584M floats <= N*MAXN*2 = 5.12M floats

    hipMemsetAsync(scal, 0, 4 * sizeof(float), stream);

    k_pre<<<(N + 255) / 256, 256, 0, stream>>>(positions, radii_in, features,
                                               posx4, radii, e_iw, e_ow, fn, scal, N);
    k_xt<<<(B * IN + 255) / 256, 256, 0, stream>>>(x, xT, B, IN);
    k_act0<<<dim3(N / BM, KSPLIT), 256, 0, stream>>>(xT, Win, partial, N, IN);
    k_act0_red<<<(N * 64) / 256, 256, 0, stream>>>(partial, e_iw, scal, actA, N);
    k_scan<<<N / SRB, 256, 0, stream>>>(posx4, scal, ep, nbr_cnt, N);
    k_weight<<<N, 256, 0, stream>>>(fn, radii, ep, nbr_cnt, rowinv, N);

    float* bufs[2] = {actA, actB};
    for (int it = 0; it < MAX_LAUNCH_ITERS; it++) {
        k_iter<<<N, 256, 0, stream>>>(bufs[it & 1], bufs[(it + 1) & 1],
                                      ep, nbr_cnt, rowinv, thr, nIter, it, N);
    }
    k_out1<<<OB, 256, 0, stream>>>(actA, actB, nIter, e_ow, scal, Wout, outPart, N);
    k_out2<<<3, 256, 0, stream>>>(outPart, (float*)d_out);
}